// Round 3
// baseline (936.557 us; speedup 1.0000x reference)
//
#include <hip/hip_runtime.h>

// ---- bf16 helpers: tables store 2 bf16 per uint (cols 2l, 2l+1) ------------
__device__ __forceinline__ float blo(unsigned u) { return __uint_as_float(u << 16); }
__device__ __forceinline__ float bhi(unsigned u) { return __uint_as_float(u & 0xffff0000u); }
__device__ __forceinline__ unsigned pack_bf16(float x, float y) {
    unsigned ux = __float_as_uint(x); ux += 0x7fffu + ((ux >> 16) & 1u);
    unsigned uy = __float_as_uint(y); uy += 0x7fffu + ((uy >> 16) & 1u);
    return (ux >> 16) | (uy & 0xffff0000u);
}

// ---------------------------------------------------------------------------
// Histogram of row indices for A and X.
// ---------------------------------------------------------------------------
__global__ void hist_kernel(const int* __restrict__ Arow, int nA,
                            const int* __restrict__ Xrow, int nX,
                            int* __restrict__ cntA, int* __restrict__ cntX) {
    int i = blockIdx.x * 256 + threadIdx.x;
    if (i < nA) {
        atomicAdd(&cntA[Arow[i]], 1);
    } else if (i < nA + nX) {
        atomicAdd(&cntX[Xrow[i - nA]], 1);
    }
}

// ---------------------------------------------------------------------------
// Hierarchical scan, stage 1: each block scans one 1024-chunk locally.
// off[i+1] = local inclusive, cnt[i] = local exclusive, chunkSums[b] = total.
// ---------------------------------------------------------------------------
__global__ __launch_bounds__(1024) void scan1_kernel(
    int* cntA, int* offA, int nA, int nchA,
    int* cntX, int* offX, int nX, int* chunkSums) {
    int b = blockIdx.x;
    int* cnt; int* off; int n; int cb;
    if (b < nchA) { cnt = cntA; off = offA; n = nA; cb = b; }
    else          { cnt = cntX; off = offX; n = nX; cb = b - nchA; }
    __shared__ int wsum[16];
    int tid = threadIdx.x, lane = tid & 63, w = tid >> 6;
    int i = cb * 1024 + tid;
    int x = (i < n) ? cnt[i] : 0;
    int v = x;
    #pragma unroll
    for (int d = 1; d < 64; d <<= 1) {
        int t = __shfl_up(v, d);
        if (lane >= d) v += t;
    }
    if (lane == 63) wsum[w] = v;
    __syncthreads();
    if (tid == 0) {
        int a = 0;
        #pragma unroll
        for (int j = 0; j < 16; ++j) { int t = wsum[j]; wsum[j] = a; a += t; }
        chunkSums[b] = a;
    }
    __syncthreads();
    int incl = v + wsum[w];
    if (i < n) { off[i + 1] = incl; cnt[i] = incl - x; }
}

// ---------------------------------------------------------------------------
// Stage 2: exclusive-scan the chunk totals (wave 0: A, wave 1: X).
// ---------------------------------------------------------------------------
__global__ __launch_bounds__(128) void scan2_kernel(int* chunkSums, int nchA, int nchX) {
    int lane = threadIdx.x & 63;
    int w = threadIdx.x >> 6;
    int n    = (w == 0) ? nchA : nchX;
    int base = (w == 0) ? 0 : nchA;
    int carry = 0;
    for (int s = 0; s < n; s += 64) {
        int v = (s + lane < n) ? chunkSums[base + s + lane] : 0;
        int incl = v;
        #pragma unroll
        for (int d = 1; d < 64; d <<= 1) {
            int t = __shfl_up(incl, d);
            if (lane >= d) incl += t;
        }
        int tot = __shfl(incl, 63);
        int ex = __shfl_up(incl, 1);
        if (lane == 0) ex = 0;
        if (s + lane < n) chunkSums[base + s + lane] = carry + ex;
        carry += tot;
    }
}

// ---------------------------------------------------------------------------
// Stage 3: add chunk bases -> global offsets; set off[0]=0.
// ---------------------------------------------------------------------------
__global__ void scan3_kernel(int* cntA, int* offA, int nA, int nchA,
                             int* cntX, int* offX, int nX,
                             const int* __restrict__ chunkSums) {
    int i = blockIdx.x * 256 + threadIdx.x;
    if (i < nA) {
        int b = chunkSums[i >> 10];
        cntA[i] += b; offA[i + 1] += b;
        if (i == 0) offA[0] = 0;
    } else {
        int j = i - nA;
        if (j < nX) {
            int b = chunkSums[nchA + (j >> 10)];
            cntX[j] += b; offX[j + 1] += b;
            if (j == 0) offX[0] = 0;
        }
    }
}

// ---------------------------------------------------------------------------
// Scatter COO -> packed CSR (one int2{col,val} 8B write per edge).
// ---------------------------------------------------------------------------
__global__ void scatter_kernel(const int* __restrict__ Arow, const int* __restrict__ Acol,
                               const float* __restrict__ Aval, int nA,
                               const int* __restrict__ Xrow, const int* __restrict__ Xcol,
                               const float* __restrict__ Xval, int nX,
                               int* __restrict__ curA, int2* __restrict__ csrA,
                               int* __restrict__ curX, int2* __restrict__ csrX) {
    int i = blockIdx.x * 256 + threadIdx.x;
    if (i < nA) {
        int r = Arow[i];
        int p = atomicAdd(&curA[r], 1);
        csrA[p] = make_int2(Acol[i], __float_as_int(Aval[i]));
    } else if (i < nA + nX) {
        int j = i - nA;
        int r = Xrow[j];
        int p = atomicAdd(&curX[r], 1);
        csrX[p] = make_int2(Xcol[j], __float_as_int(Xval[j]));
    }
}

// ---------------------------------------------------------------------------
// Transpose the three 128x128 weight matrices (coalesced per-row GEMM reads)
// and convert emb_W to the packed-bf16 gather table.
// ---------------------------------------------------------------------------
__global__ void prep_kernel(const float* __restrict__ W1, const float* __restrict__ W2,
                            const float* __restrict__ W3,
                            float* __restrict__ Wt1, float* __restrict__ Wt2,
                            float* __restrict__ Wt3,
                            const float2* __restrict__ emb, unsigned* __restrict__ emb16,
                            int nemb) {   // nemb = V*64
    int gid = blockIdx.x * 256 + threadIdx.x;
    if (gid < 3 * 16384) {
        int m = gid >> 14;
        int idx = gid & 16383;
        int j = idx >> 7;
        int k = idx & 127;
        const float* W = (m == 0) ? W1 : (m == 1) ? W2 : W3;
        float*      Wt = (m == 0) ? Wt1 : (m == 1) ? Wt2 : Wt3;
        Wt[k * 128 + j] = W[j * 128 + k];
    }
    int e = gid - 3 * 16384;
    if (e >= 0 && e < nemb) {
        float2 f = emb[e];
        emb16[e] = pack_bf16(f.x, f.y);
    }
}

// ---------------------------------------------------------------------------
// SpMM gather-reduce for one row, half-wave edge pairing:
//   lanes 0-31 (h=0) take even edges, lanes 32-63 (h=1) odd edges.
//   Lane's quarter q=lane&31 covers cols 4q..4q+3 (uint2 = 4 bf16).
//   x4 manual unroll -> 8 edges in flight per wave.
// Returns per-lane partial sums in a0..a3; caller xor-combines halves.
// ---------------------------------------------------------------------------
__device__ __forceinline__ void spmm_row(const int2* __restrict__ csr, int s, int e,
                                         const uint2* __restrict__ in2, int h, int q,
                                         float& a0, float& a1, float& a2, float& a3) {
    int idx = s + h;
    for (; idx + 6 < e; idx += 8) {
        int2 cv0 = csr[idx], cv1 = csr[idx + 2], cv2 = csr[idx + 4], cv3 = csr[idx + 6];
        uint2 x0 = in2[(size_t)cv0.x * 32 + q];
        uint2 x1 = in2[(size_t)cv1.x * 32 + q];
        uint2 x2 = in2[(size_t)cv2.x * 32 + q];
        uint2 x3 = in2[(size_t)cv3.x * 32 + q];
        float v0 = __int_as_float(cv0.y), v1 = __int_as_float(cv1.y);
        float v2 = __int_as_float(cv2.y), v3 = __int_as_float(cv3.y);
        a0 += v0 * blo(x0.x) + v1 * blo(x1.x) + v2 * blo(x2.x) + v3 * blo(x3.x);
        a1 += v0 * bhi(x0.x) + v1 * bhi(x1.x) + v2 * bhi(x2.x) + v3 * bhi(x3.x);
        a2 += v0 * blo(x0.y) + v1 * blo(x1.y) + v2 * blo(x2.y) + v3 * blo(x3.y);
        a3 += v0 * bhi(x0.y) + v1 * bhi(x1.y) + v2 * bhi(x2.y) + v3 * bhi(x3.y);
    }
    for (; idx < e; idx += 2) {
        int2 cv = csr[idx];
        uint2 x = in2[(size_t)cv.x * 32 + q];
        float v = __int_as_float(cv.y);
        a0 += v * blo(x.x); a1 += v * bhi(x.x);
        a2 += v * blo(x.y); a3 += v * bhi(x.y);
    }
}

// ---------------------------------------------------------------------------
// Fused layer kernel (templated rows-per-wave). One wave owns R rows.
//   mode 0: out = bf16(relu(spmm(A,in) @ W^T))
//   mode 1: t = relu(spmm(A,in) @ W^T); u = 0.3*emb + 0.7*t;
//           out = bf16(layernorm(u)*g + b + emb)   (word_H + emb_W pre-fused)
// No __syncthreads: LDS slices are wave-private.
// ---------------------------------------------------------------------------
template <int R>
__global__ __launch_bounds__(256) void layer_kernel(
    const int* __restrict__ off, const int2* __restrict__ csr,
    const unsigned* __restrict__ in,          // bf16-packed [nrows][64]
    const float2* __restrict__ Wt,            // [128][64] float2 view
    const float2* __restrict__ emb,           // fp32, mode 1 only
    const float* __restrict__ g, const float* __restrict__ bb,  // mode 1 only
    unsigned* __restrict__ out, int nrows, int mode) {

    __shared__ float acc_s[4][R][128];
    int lane = threadIdx.x & 63;
    int wave = threadIdx.x >> 6;
    int h = lane >> 5;
    int q = lane & 31;
    const uint2* in2 = (const uint2*)in;
    int rowbase = (blockIdx.x * 4 + wave) * R;

    // --- SpMM into wave-private LDS ---
    for (int r = 0; r < R; ++r) {
        int row = rowbase + r;
        float a0 = 0.f, a1 = 0.f, a2 = 0.f, a3 = 0.f;
        if (row < nrows) {
            spmm_row(csr, off[row], off[row + 1], in2, h, q, a0, a1, a2, a3);
        }
        a0 += __shfl_xor(a0, 32);
        a1 += __shfl_xor(a1, 32);
        a2 += __shfl_xor(a2, 32);
        a3 += __shfl_xor(a3, 32);
        if (h == 0) *(float4*)&acc_s[wave][r][4 * q] = make_float4(a0, a1, a2, a3);
    }

    // --- dense 128x128 GEMM: o[r][j] = sum_k acc[r][k] * Wt[k][j] ---
    float2 o[R];
    #pragma unroll
    for (int r = 0; r < R; ++r) o[r] = make_float2(0.f, 0.f);
    for (int k = 0; k < 128; k += 2) {
        float2 w0 = Wt[(size_t)k * 64 + lane];
        float2 w1 = Wt[(size_t)(k + 1) * 64 + lane];
        #pragma unroll
        for (int r = 0; r < R; ++r) {
            float b0 = acc_s[wave][r][k];
            float b1 = acc_s[wave][r][k + 1];
            o[r].x += b0 * w0.x + b1 * w1.x;
            o[r].y += b0 * w0.y + b1 * w1.y;
        }
    }

    // --- epilogue ---
    for (int r = 0; r < R; ++r) {
        int row = rowbase + r;
        if (row >= nrows) break;
        float hx = fmaxf(o[r].x, 0.f), hy = fmaxf(o[r].y, 0.f);
        if (mode == 0) {
            out[(size_t)row * 64 + lane] = pack_bf16(hx, hy);
        } else {
            float2 e2 = emb[(size_t)row * 64 + lane];
            float ux = 0.3f * e2.x + 0.7f * hx;
            float uy = 0.3f * e2.y + 0.7f * hy;
            float s = ux + uy;
            #pragma unroll
            for (int d = 1; d < 64; d <<= 1) s += __shfl_xor(s, d);
            float mu = s * (1.f / 128.f);
            float dx = ux - mu, dy = uy - mu;
            float qv = dx * dx + dy * dy;
            #pragma unroll
            for (int d = 1; d < 64; d <<= 1) qv += __shfl_xor(qv, d);
            float rstd = rsqrtf(qv * (1.f / 128.f) + 1e-5f);
            float2 gg = *(const float2*)&g[2 * lane];
            float2 b2 = *(const float2*)&bb[2 * lane];
            float wx = dx * rstd * gg.x + b2.x + e2.x;   // word_H + emb_W fused
            float wy = dy * rstd * gg.y + b2.y + e2.y;
            out[(size_t)row * 64 + lane] = pack_bf16(wx, wy);
        }
    }
}

// ---------------------------------------------------------------------------
// Doc kernel: spmm(X, word_sum[bf16]) -> relu(. @ mlp_W^T + b) -> clf logits.
// ---------------------------------------------------------------------------
template <int R>
__global__ __launch_bounds__(256) void doc_kernel(
    const int* __restrict__ off, const int2* __restrict__ csr,
    const unsigned* __restrict__ in,          // bf16-packed word_sum [V][64]
    const float2* __restrict__ Wt,            // mlp_W transposed, float2 view
    const float* __restrict__ mlp_b, const float* __restrict__ clfW,
    const float* __restrict__ clfb,
    float* __restrict__ outp, int nrows) {

    __shared__ float acc_s[4][R][128];
    int lane = threadIdx.x & 63;
    int wave = threadIdx.x >> 6;
    int h = lane >> 5;
    int q = lane & 31;
    const uint2* in2 = (const uint2*)in;
    int rowbase = (blockIdx.x * 4 + wave) * R;

    for (int r = 0; r < R; ++r) {
        int row = rowbase + r;
        float a0 = 0.f, a1 = 0.f, a2 = 0.f, a3 = 0.f;
        if (row < nrows) {
            spmm_row(csr, off[row], off[row + 1], in2, h, q, a0, a1, a2, a3);
        }
        a0 += __shfl_xor(a0, 32);
        a1 += __shfl_xor(a1, 32);
        a2 += __shfl_xor(a2, 32);
        a3 += __shfl_xor(a3, 32);
        if (h == 0) *(float4*)&acc_s[wave][r][4 * q] = make_float4(a0, a1, a2, a3);
    }

    float2 o[R];
    #pragma unroll
    for (int r = 0; r < R; ++r) o[r] = make_float2(0.f, 0.f);
    for (int k = 0; k < 128; k += 2) {
        float2 w0 = Wt[(size_t)k * 64 + lane];
        float2 w1 = Wt[(size_t)(k + 1) * 64 + lane];
        #pragma unroll
        for (int r = 0; r < R; ++r) {
            float b0 = acc_s[wave][r][k];
            float b1 = acc_s[wave][r][k + 1];
            o[r].x += b0 * w0.x + b1 * w1.x;
            o[r].y += b0 * w0.y + b1 * w1.y;
        }
    }

    float2 mb = *(const float2*)&mlp_b[2 * lane];
    float2 c0 = *(const float2*)&clfW[2 * lane];
    float2 c1 = *(const float2*)&clfW[128 + 2 * lane];
    for (int r = 0; r < R; ++r) {
        int row = rowbase + r;
        if (row >= nrows) break;
        float hx = fmaxf(o[r].x + mb.x, 0.f);
        float hy = fmaxf(o[r].y + mb.y, 0.f);
        float p0 = hx * c0.x + hy * c0.y;
        float p1 = hx * c1.x + hy * c1.y;
        #pragma unroll
        for (int d = 1; d < 64; d <<= 1) {
            p0 += __shfl_xor(p0, d);
            p1 += __shfl_xor(p1, d);
        }
        if (lane == 0) {
            outp[(size_t)row * 2 + 0] = p0 + clfb[0];
            outp[(size_t)row * 2 + 1] = p1 + clfb[1];
        }
    }
}

// ---------------------------------------------------------------------------
extern "C" void kernel_launch(void* const* d_in, const int* in_sizes, int n_in,
                              void* d_out, int out_size, void* d_ws, size_t ws_size,
                              hipStream_t stream) {
    const int*   A_row  = (const int*)d_in[0];
    const int*   A_col  = (const int*)d_in[1];
    const float* A_val  = (const float*)d_in[2];
    const int*   X_row  = (const int*)d_in[3];
    const int*   X_col  = (const int*)d_in[4];
    const float* X_val  = (const float*)d_in[5];
    const float* emb_W  = (const float*)d_in[6];
    const float* lin1_W = (const float*)d_in[7];
    const float* lin2_W = (const float*)d_in[8];
    const float* norm_g = (const float*)d_in[9];
    const float* norm_b = (const float*)d_in[10];
    const float* mlp_W  = (const float*)d_in[11];
    const float* mlp_b  = (const float*)d_in[12];
    const float* clf_W  = (const float*)d_in[13];
    const float* clf_b  = (const float*)d_in[14];

    const int E   = in_sizes[0];
    const int NNZ = in_sizes[3];
    const int V   = in_sizes[6] / 128;
    const int D   = out_size / 2;   // N_DOCS
    const int nchA = (V + 1023) / 1024;
    const int nchX = (D + 1023) / 1024;

    // workspace carve-up (256B aligned)
    char* p = (char*)d_ws;
    auto alloc = [&](size_t bytes) -> void* {
        void* q = (void*)p;
        p += (bytes + 255) & ~(size_t)255;
        return q;
    };
    int*      curA   = (int*)alloc((size_t)V * 4);
    int*      offA   = (int*)alloc((size_t)(V + 1) * 4);
    int2*     csrA   = (int2*)alloc((size_t)E * 8);
    int*      curX   = (int*)alloc((size_t)D * 4);
    int*      offX   = (int*)alloc((size_t)(D + 1) * 4);
    int2*     csrX   = (int2*)alloc((size_t)NNZ * 8);
    int*      chunkS = (int*)alloc((size_t)(nchA + nchX) * 4);
    float*    Wt1    = (float*)alloc(128 * 128 * 4);
    float*    Wt2    = (float*)alloc(128 * 128 * 4);
    float*    Wt3    = (float*)alloc(128 * 128 * 4);
    unsigned* EMB16  = (unsigned*)alloc((size_t)V * 64 * 4);  // bf16-packed emb
    unsigned* H1     = (unsigned*)alloc((size_t)V * 64 * 4);  // bf16-packed
    unsigned* WS     = (unsigned*)alloc((size_t)V * 64 * 4);  // bf16-packed word_H+emb

    hipMemsetAsync(curA, 0, (size_t)V * 4, stream);
    hipMemsetAsync(curX, 0, (size_t)D * 4, stream);

    int tot = E + NNZ;
    hist_kernel<<<(tot + 255) / 256, 256, 0, stream>>>(A_row, E, X_row, NNZ, curA, curX);
    scan1_kernel<<<nchA + nchX, 1024, 0, stream>>>(curA, offA, V, nchA, curX, offX, D, chunkS);
    scan2_kernel<<<1, 128, 0, stream>>>(chunkS, nchA, nchX);
    scan3_kernel<<<(V + D + 255) / 256, 256, 0, stream>>>(curA, offA, V, nchA, curX, offX, D, chunkS);
    scatter_kernel<<<(tot + 255) / 256, 256, 0, stream>>>(
        A_row, A_col, A_val, E, X_row, X_col, X_val, NNZ,
        curA, csrA, curX, csrX);
    prep_kernel<<<(3 * 16384 + V * 64 + 255) / 256, 256, 0, stream>>>(
        lin1_W, lin2_W, mlp_W, Wt1, Wt2, Wt3, (const float2*)emb_W, EMB16, V * 64);

    int layer_blocks = (V + 4 * 4 - 1) / (4 * 4);
    layer_kernel<4><<<layer_blocks, 256, 0, stream>>>(
        offA, csrA, EMB16, (const float2*)Wt1,
        nullptr, nullptr, nullptr, H1, V, 0);
    layer_kernel<4><<<layer_blocks, 256, 0, stream>>>(
        offA, csrA, H1, (const float2*)Wt2,
        (const float2*)emb_W, norm_g, norm_b, WS, V, 1);

    int doc_blocks = (D + 4 * 2 - 1) / (4 * 2);
    doc_kernel<2><<<doc_blocks, 256, 0, stream>>>(
        offX, csrX, WS, (const float2*)Wt3,
        mlp_b, clf_W, clf_b, (float*)d_out, D);
}